// Round 4
// baseline (56.343 us; speedup 1.0000x reference)
//
#include <hip/hip_runtime.h>
#include <hip/hip_bf16.h>

#define NNODES 100000
#define DIMF   128
#define NB     32768
#define KNEI   25
#define UNITS  128
#define KDIM   256   // 2*DIMF
#define BM     16    // rows per block

typedef __bf16 bf16x8 __attribute__((ext_vector_type(8)));
typedef float  f32x4  __attribute__((ext_vector_type(4)));
typedef float  f32x2  __attribute__((ext_vector_type(2)));
typedef unsigned short u16x8 __attribute__((ext_vector_type(8)));

#if defined(__has_builtin)
#if __has_builtin(__builtin_amdgcn_cvt_pk_f32_fp8) && __has_builtin(__builtin_amdgcn_cvt_pk_fp8_f32)
#define HAVE_FP8_CVT 1
#endif
#endif
#ifndef HAVE_FP8_CVT
#define HAVE_FP8_CVT 0
#endif

__device__ __forceinline__ unsigned short bf16u(float x) {
    __hip_bfloat16 h = __float2bfloat16(x);
    return __builtin_bit_cast(unsigned short, h);
}

// Convert W (256x128 f32, row-major) -> Wt (128x256 bf16, row-major = W^T)
__global__ void wconv_kernel(const float* __restrict__ W,
                             unsigned short* __restrict__ Wt) {
    int i = blockIdx.x * 256 + threadIdx.x;   // 0..32767
    int n = i >> 8;                           // 0..127 (output unit)
    int k = i & 255;                          // 0..255 (concat dim)
    Wt[n * KDIM + k] = bf16u(W[k * UNITS + n]);
}

// ======================= fp8 path =======================
#if HAVE_FP8_CVT
// features f32 -> fp8 e4m3 table (100000x128 = 12.8 MB). 8 elems/thread.
__global__ __launch_bounds__(256) void fconv_fp8_kernel(const float* __restrict__ F,
                                                        unsigned int* __restrict__ T) {
    int i = blockIdx.x * 256 + threadIdx.x;   // 0..1,599,999
    const float4* f4 = (const float4*)F;
    float4 a = f4[(size_t)i * 2];
    float4 b = f4[(size_t)i * 2 + 1];
    int w0 = __builtin_amdgcn_cvt_pk_fp8_f32(a.x, a.y, 0, false);
    w0     = __builtin_amdgcn_cvt_pk_fp8_f32(a.z, a.w, w0, true);
    int w1 = __builtin_amdgcn_cvt_pk_fp8_f32(b.x, b.y, 0, false);
    w1     = __builtin_amdgcn_cvt_pk_fp8_f32(b.z, b.w, w1, true);
    uint2 o; o.x = (unsigned int)w0; o.y = (unsigned int)w1;
    *(uint2*)(T + (size_t)i * 2) = o;
}

// Fused: node gather from f32 features, neighbor-mean gather from fp8 table.
__global__ __launch_bounds__(256) void fused_fp8_kernel(
    const float* __restrict__ features,
    const unsigned char* __restrict__ ftab8,   // fp8 e4m3 [NNODES][DIMF]
    const int*   __restrict__ node,
    const int*   __restrict__ neigh,
    const unsigned short* __restrict__ Wt,
    float* __restrict__ out)
{
    __shared__ unsigned short lds[BM * KDIM];   // 8 KB, XOR-swizzled concat tile

    const int tid = threadIdx.x;
    const int blk = blockIdx.x;

    // ---------------- Phase 1: gather + mean -> LDS ----------------
    const int lane8 = tid & 15;                 // dims [lane8*8, lane8*8+8)
    const int row   = tid >> 4;                 // 0..15
    const int g     = blk * BM + row;

    // node half: f32 features -> bf16 LDS
    const int nidx = node[g];
    const float4* nf4 = (const float4*)(features + (size_t)nidx * DIMF + lane8 * 8);
    float4 na = nf4[0];
    float4 nb4 = nf4[1];
    u16x8 pn;
    pn[0] = bf16u(na.x);  pn[1] = bf16u(na.y);  pn[2] = bf16u(na.z);  pn[3] = bf16u(na.w);
    pn[4] = bf16u(nb4.x); pn[5] = bf16u(nb4.y); pn[6] = bf16u(nb4.z); pn[7] = bf16u(nb4.w);
    const int off0 = (row * 512 + lane8 * 16) ^ ((row & 7) << 4);
    *(u16x8*)((char*)lds + off0) = pn;

    // neighbor mean from fp8 table
    float acc[8];
    #pragma unroll
    for (int j = 0; j < 8; ++j) acc[j] = 0.f;
    const int* nb = neigh + (size_t)g * KNEI;
    #pragma unroll
    for (int k = 0; k < KNEI; ++k) {
        uint2 v = *(const uint2*)(ftab8 + (size_t)nb[k] * DIMF + lane8 * 8);
        f32x2 p0 = __builtin_amdgcn_cvt_pk_f32_fp8((int)v.x, false);
        f32x2 p1 = __builtin_amdgcn_cvt_pk_f32_fp8((int)v.x, true);
        f32x2 p2 = __builtin_amdgcn_cvt_pk_f32_fp8((int)v.y, false);
        f32x2 p3 = __builtin_amdgcn_cvt_pk_f32_fp8((int)v.y, true);
        acc[0] += p0[0]; acc[1] += p0[1]; acc[2] += p1[0]; acc[3] += p1[1];
        acc[4] += p2[0]; acc[5] += p2[1]; acc[6] += p3[0]; acc[7] += p3[1];
    }
    u16x8 pm;
    const float s = 1.0f / 25.0f;
    #pragma unroll
    for (int j = 0; j < 8; ++j) pm[j] = bf16u(acc[j] * s);
    const int off1 = (row * 512 + 256 + lane8 * 16) ^ ((row & 7) << 4);
    *(u16x8*)((char*)lds + off1) = pm;

    __syncthreads();

    // ---------------- Phase 2: MFMA GEMM (16x256) x (256x128) ----------------
    const int wv      = tid >> 6;               // 0..3 -> 32-col slice
    const int lane    = tid & 63;
    const int l15     = lane & 15;
    const int khalf   = lane >> 4;              // 0..3
    const int colbase = wv * 32;

    f32x4 acc00 = {0.f,0.f,0.f,0.f};
    f32x4 acc01 = {0.f,0.f,0.f,0.f};

    #pragma unroll
    for (int ks = 0; ks < 8; ++ks) {
        const int ke = ks * 32 + khalf * 8;

        const int row0  = l15;
        const int byte0 = (row0 * 512 + ke * 2) ^ ((row0 & 7) << 4);
        bf16x8 a0 = *(const bf16x8*)((const char*)lds + byte0);

        bf16x8 b0 = *(const bf16x8*)(Wt + (size_t)(colbase + l15)      * KDIM + ke);
        bf16x8 b1 = *(const bf16x8*)(Wt + (size_t)(colbase + 16 + l15) * KDIM + ke);

        acc00 = __builtin_amdgcn_mfma_f32_16x16x32_bf16(a0, b0, acc00, 0, 0, 0);
        acc01 = __builtin_amdgcn_mfma_f32_16x16x32_bf16(a0, b1, acc01, 0, 0, 0);
    }

    #pragma unroll
    for (int i = 0; i < 4; ++i) {
        const int r0 = blk * BM + khalf * 4 + i;
        const int c0 = colbase + l15;
        const int c1 = c0 + 16;
        out[(size_t)r0 * UNITS + c0] = fmaxf(acc00[i], 0.f);
        out[(size_t)r0 * UNITS + c1] = fmaxf(acc01[i], 0.f);
    }
}
#endif // HAVE_FP8_CVT

// ======================= bf16-table fallback path (R3, proven) =======================
__global__ __launch_bounds__(256) void fconv_kernel(const float* __restrict__ F,
                                                    unsigned short* __restrict__ T) {
    int i = blockIdx.x * 256 + threadIdx.x;
    const float4* f4 = (const float4*)F;
    float4 a = f4[(size_t)i * 2];
    float4 b = f4[(size_t)i * 2 + 1];
    u16x8 o;
    o[0] = bf16u(a.x); o[1] = bf16u(a.y); o[2] = bf16u(a.z); o[3] = bf16u(a.w);
    o[4] = bf16u(b.x); o[5] = bf16u(b.y); o[6] = bf16u(b.z); o[7] = bf16u(b.w);
    *(u16x8*)(T + (size_t)i * 8) = o;
}

__global__ __launch_bounds__(256) void fused_bf16_kernel(
    const unsigned short* __restrict__ ftab,
    const int*   __restrict__ node,
    const int*   __restrict__ neigh,
    const unsigned short* __restrict__ Wt,
    float* __restrict__ out)
{
    __shared__ unsigned short lds[BM * KDIM];

    const int tid = threadIdx.x;
    const int blk = blockIdx.x;

    const int lane8 = tid & 15;
    const int row   = tid >> 4;
    const int g     = blk * BM + row;

    const int nidx = node[g];
    u16x8 nf = *(const u16x8*)(ftab + (size_t)nidx * DIMF + lane8 * 8);
    const int off0 = (row * 512 + lane8 * 16) ^ ((row & 7) << 4);
    *(u16x8*)((char*)lds + off0) = nf;

    float acc[8];
    #pragma unroll
    for (int j = 0; j < 8; ++j) acc[j] = 0.f;
    const int* nb = neigh + (size_t)g * KNEI;
    #pragma unroll
    for (int k = 0; k < KNEI; ++k) {
        u16x8 v = *(const u16x8*)(ftab + (size_t)nb[k] * DIMF + lane8 * 8);
        #pragma unroll
        for (int j = 0; j < 8; ++j) {
            unsigned int u = ((unsigned int)v[j]) << 16;
            acc[j] += __builtin_bit_cast(float, u);
        }
    }
    u16x8 pm;
    const float s = 1.0f / 25.0f;
    #pragma unroll
    for (int j = 0; j < 8; ++j) pm[j] = bf16u(acc[j] * s);
    const int off1 = (row * 512 + 256 + lane8 * 16) ^ ((row & 7) << 4);
    *(u16x8*)((char*)lds + off1) = pm;

    __syncthreads();

    const int wv      = tid >> 6;
    const int lane    = tid & 63;
    const int l15     = lane & 15;
    const int khalf   = lane >> 4;
    const int colbase = wv * 32;

    f32x4 acc00 = {0.f,0.f,0.f,0.f};
    f32x4 acc01 = {0.f,0.f,0.f,0.f};

    #pragma unroll
    for (int ks = 0; ks < 8; ++ks) {
        const int ke = ks * 32 + khalf * 8;

        const int row0  = l15;
        const int byte0 = (row0 * 512 + ke * 2) ^ ((row0 & 7) << 4);
        bf16x8 a0 = *(const bf16x8*)((const char*)lds + byte0);

        bf16x8 b0 = *(const bf16x8*)(Wt + (size_t)(colbase + l15)      * KDIM + ke);
        bf16x8 b1 = *(const bf16x8*)(Wt + (size_t)(colbase + 16 + l15) * KDIM + ke);

        acc00 = __builtin_amdgcn_mfma_f32_16x16x32_bf16(a0, b0, acc00, 0, 0, 0);
        acc01 = __builtin_amdgcn_mfma_f32_16x16x32_bf16(a0, b1, acc01, 0, 0, 0);
    }

    #pragma unroll
    for (int i = 0; i < 4; ++i) {
        const int r0 = blk * BM + khalf * 4 + i;
        const int c0 = colbase + l15;
        const int c1 = c0 + 16;
        out[(size_t)r0 * UNITS + c0] = fmaxf(acc00[i], 0.f);
        out[(size_t)r0 * UNITS + c1] = fmaxf(acc01[i], 0.f);
    }
}

// ======================= f32 direct fallback (tiny ws) =======================
__global__ __launch_bounds__(256) void fused_kernel(
    const float* __restrict__ features,
    const int*   __restrict__ node,
    const int*   __restrict__ neigh,
    const unsigned short* __restrict__ Wt,
    float* __restrict__ out)
{
    __shared__ unsigned short lds[BM * KDIM];

    const int tid = threadIdx.x;
    const int blk = blockIdx.x;

    const int lane4 = tid & 31;
    const int rgrp  = tid >> 5;
    const float4* feat4 = (const float4*)features;

    #pragma unroll
    for (int rr = 0; rr < 2; ++rr) {
        const int row = rr * 8 + rgrp;
        const int g   = blk * BM + row;

        const int nidx = node[g];
        float4 nf = feat4[(size_t)nidx * 32 + lane4];

        float4 acc; acc.x = 0.f; acc.y = 0.f; acc.z = 0.f; acc.w = 0.f;
        const int* nb = neigh + (size_t)g * KNEI;
        #pragma unroll
        for (int k = 0; k < KNEI; ++k) {
            const int idx = nb[k];
            float4 v = feat4[(size_t)idx * 32 + lane4];
            acc.x += v.x; acc.y += v.y; acc.z += v.z; acc.w += v.w;
        }
        const float s = 1.0f / 25.0f;
        acc.x *= s; acc.y *= s; acc.z *= s; acc.w *= s;

        ushort4 pn; pn.x = bf16u(nf.x); pn.y = bf16u(nf.y); pn.z = bf16u(nf.z); pn.w = bf16u(nf.w);
        int off0 = (row * 512 + lane4 * 8) ^ ((row & 7) << 4);
        *(ushort4*)((char*)lds + off0) = pn;

        ushort4 pm; pm.x = bf16u(acc.x); pm.y = bf16u(acc.y); pm.z = bf16u(acc.z); pm.w = bf16u(acc.w);
        int off1 = (row * 512 + 256 + lane4 * 8) ^ ((row & 7) << 4);
        *(ushort4*)((char*)lds + off1) = pm;
    }

    __syncthreads();

    const int wv      = tid >> 6;
    const int lane    = tid & 63;
    const int l15     = lane & 15;
    const int khalf   = lane >> 4;
    const int colbase = wv * 32;

    f32x4 acc00 = {0.f,0.f,0.f,0.f};
    f32x4 acc01 = {0.f,0.f,0.f,0.f};

    #pragma unroll
    for (int ks = 0; ks < 8; ++ks) {
        const int ke = ks * 32 + khalf * 8;

        const int row0  = l15;
        const int byte0 = (row0 * 512 + ke * 2) ^ ((row0 & 7) << 4);
        bf16x8 a0 = *(const bf16x8*)((const char*)lds + byte0);

        bf16x8 b0 = *(const bf16x8*)(Wt + (size_t)(colbase + l15)      * KDIM + ke);
        bf16x8 b1 = *(const bf16x8*)(Wt + (size_t)(colbase + 16 + l15) * KDIM + ke);

        acc00 = __builtin_amdgcn_mfma_f32_16x16x32_bf16(a0, b0, acc00, 0, 0, 0);
        acc01 = __builtin_amdgcn_mfma_f32_16x16x32_bf16(a0, b1, acc01, 0, 0, 0);
    }

    #pragma unroll
    for (int i = 0; i < 4; ++i) {
        const int r0 = blk * BM + khalf * 4 + i;
        const int c0 = colbase + l15;
        const int c1 = c0 + 16;
        out[(size_t)r0 * UNITS + c0] = fmaxf(acc00[i], 0.f);
        out[(size_t)r0 * UNITS + c1] = fmaxf(acc01[i], 0.f);
    }
}

extern "C" void kernel_launch(void* const* d_in, const int* in_sizes, int n_in,
                              void* d_out, int out_size, void* d_ws, size_t ws_size,
                              hipStream_t stream) {
    const float* features = (const float*)d_in[0];
    const int*   node     = (const int*)d_in[1];
    const int*   neigh    = (const int*)d_in[2];
    const float* W        = (const float*)d_in[3];
    float* out            = (float*)d_out;

    unsigned short* Wt = (unsigned short*)d_ws;                    // 64 KB
    const size_t tab_off = 65536;

    wconv_kernel<<<128, 256, 0, stream>>>(W, Wt);

#if HAVE_FP8_CVT
    const size_t fp8_bytes = (size_t)NNODES * DIMF;                // 12.8 MB
    if (ws_size >= tab_off + fp8_bytes) {
        unsigned char* ftab8 = (unsigned char*)d_ws + tab_off;
        fconv_fp8_kernel<<<6250, 256, 0, stream>>>(features, (unsigned int*)ftab8);
        fused_fp8_kernel<<<NB / BM, 256, 0, stream>>>(features, ftab8, node, neigh, Wt, out);
        return;
    }
#endif
    const size_t bf16_bytes = (size_t)NNODES * DIMF * 2;           // 25.6 MB
    if (ws_size >= tab_off + bf16_bytes) {
        unsigned short* ftab = (unsigned short*)((char*)d_ws + tab_off);
        fconv_kernel<<<6250, 256, 0, stream>>>(features, ftab);
        fused_bf16_kernel<<<NB / BM, 256, 0, stream>>>(ftab, node, neigh, Wt, out);
    } else {
        fused_kernel<<<NB / BM, 256, 0, stream>>>(features, node, neigh, Wt, out);
    }
}

// Round 5
// 47.060 us; speedup vs baseline: 1.1973x; 1.1973x over previous
//
#include <hip/hip_runtime.h>
#include <hip/hip_bf16.h>

#define NNODES 100000
#define DIMF   128
#define NB     32768
#define KNEI   25
#define UNITS  128
#define KDIM   256   // 2*DIMF
#define BM     16    // rows per block

typedef __bf16 bf16x8 __attribute__((ext_vector_type(8)));
typedef float  f32x4  __attribute__((ext_vector_type(4)));
typedef float  f32x2  __attribute__((ext_vector_type(2)));
typedef unsigned short u16x8 __attribute__((ext_vector_type(8)));

__device__ __forceinline__ unsigned short bf16u(float x) {
    __hip_bfloat16 h = __float2bfloat16(x);
    return __builtin_bit_cast(unsigned short, h);
}

// Convert W (256x128 f32, row-major) -> Wt (128x256 bf16, row-major = W^T)
__global__ void wconv_kernel(const float* __restrict__ W,
                             unsigned short* __restrict__ Wt) {
    int i = blockIdx.x * 256 + threadIdx.x;   // 0..32767
    int n = i >> 8;                           // 0..127 (output unit)
    int k = i & 255;                          // 0..255 (concat dim)
    Wt[n * KDIM + k] = bf16u(W[k * UNITS + n]);
}

// ======================= fp8 path (primary) =======================
// features f32 -> fp8 e4m3 table (100000x128 = 12.8 MB). 8 elems/thread.
__global__ __launch_bounds__(256) void fconv_fp8_kernel(const float* __restrict__ F,
                                                        unsigned int* __restrict__ T) {
    int i = blockIdx.x * 256 + threadIdx.x;   // 0..1,599,999
    const float4* f4 = (const float4*)F;
    float4 a = f4[(size_t)i * 2];
    float4 b = f4[(size_t)i * 2 + 1];
    int w0 = __builtin_amdgcn_cvt_pk_fp8_f32(a.x, a.y, 0, false);
    w0     = __builtin_amdgcn_cvt_pk_fp8_f32(a.z, a.w, w0, true);
    int w1 = __builtin_amdgcn_cvt_pk_fp8_f32(b.x, b.y, 0, false);
    w1     = __builtin_amdgcn_cvt_pk_fp8_f32(b.z, b.w, w1, true);
    uint2 o; o.x = (unsigned int)w0; o.y = (unsigned int)w1;
    *(uint2*)(T + (size_t)i * 2) = o;
}

// Fused: node gather from f32 features, neighbor-mean gather from fp8 table.
__global__ __launch_bounds__(256) void fused_fp8_kernel(
    const float* __restrict__ features,
    const unsigned char* __restrict__ ftab8,   // fp8 e4m3 [NNODES][DIMF]
    const int*   __restrict__ node,
    const int*   __restrict__ neigh,
    const unsigned short* __restrict__ Wt,
    float* __restrict__ out)
{
    __shared__ unsigned short lds[BM * KDIM];   // 8 KB, XOR-swizzled concat tile

    const int tid = threadIdx.x;
    const int blk = blockIdx.x;

    // ---------------- Phase 1: gather + mean -> LDS ----------------
    const int lane8 = tid & 15;                 // dims [lane8*8, lane8*8+8)
    const int row   = tid >> 4;                 // 0..15
    const int g     = blk * BM + row;

    // node half: f32 features -> bf16 LDS
    const int nidx = node[g];
    const float4* nf4 = (const float4*)(features + (size_t)nidx * DIMF + lane8 * 8);
    float4 na  = nf4[0];
    float4 nb4 = nf4[1];
    u16x8 pn;
    pn[0] = bf16u(na.x);  pn[1] = bf16u(na.y);  pn[2] = bf16u(na.z);  pn[3] = bf16u(na.w);
    pn[4] = bf16u(nb4.x); pn[5] = bf16u(nb4.y); pn[6] = bf16u(nb4.z); pn[7] = bf16u(nb4.w);
    const int off0 = (row * 512 + lane8 * 16) ^ ((row & 7) << 4);
    *(u16x8*)((char*)lds + off0) = pn;

    // neighbor mean from fp8 table (HW decode: v_cvt_pk_f32_fp8)
    float acc[8];
    #pragma unroll
    for (int j = 0; j < 8; ++j) acc[j] = 0.f;
    const int* nb = neigh + (size_t)g * KNEI;
    #pragma unroll
    for (int k = 0; k < KNEI; ++k) {
        uint2 v = *(const uint2*)(ftab8 + (size_t)nb[k] * DIMF + lane8 * 8);
        f32x2 p0 = __builtin_amdgcn_cvt_pk_f32_fp8((int)v.x, false);
        f32x2 p1 = __builtin_amdgcn_cvt_pk_f32_fp8((int)v.x, true);
        f32x2 p2 = __builtin_amdgcn_cvt_pk_f32_fp8((int)v.y, false);
        f32x2 p3 = __builtin_amdgcn_cvt_pk_f32_fp8((int)v.y, true);
        acc[0] += p0[0]; acc[1] += p0[1]; acc[2] += p1[0]; acc[3] += p1[1];
        acc[4] += p2[0]; acc[5] += p2[1]; acc[6] += p3[0]; acc[7] += p3[1];
    }
    u16x8 pm;
    const float s = 1.0f / 25.0f;
    #pragma unroll
    for (int j = 0; j < 8; ++j) pm[j] = bf16u(acc[j] * s);
    const int off1 = (row * 512 + 256 + lane8 * 16) ^ ((row & 7) << 4);
    *(u16x8*)((char*)lds + off1) = pm;

    __syncthreads();

    // ---------------- Phase 2: MFMA GEMM (16x256) x (256x128) ----------------
    const int wv      = tid >> 6;               // 0..3 -> 32-col slice
    const int lane    = tid & 63;
    const int l15     = lane & 15;
    const int khalf   = lane >> 4;              // 0..3
    const int colbase = wv * 32;

    f32x4 acc00 = {0.f,0.f,0.f,0.f};
    f32x4 acc01 = {0.f,0.f,0.f,0.f};

    #pragma unroll
    for (int ks = 0; ks < 8; ++ks) {
        const int ke = ks * 32 + khalf * 8;

        const int row0  = l15;
        const int byte0 = (row0 * 512 + ke * 2) ^ ((row0 & 7) << 4);
        bf16x8 a0 = *(const bf16x8*)((const char*)lds + byte0);

        bf16x8 b0 = *(const bf16x8*)(Wt + (size_t)(colbase + l15)      * KDIM + ke);
        bf16x8 b1 = *(const bf16x8*)(Wt + (size_t)(colbase + 16 + l15) * KDIM + ke);

        acc00 = __builtin_amdgcn_mfma_f32_16x16x32_bf16(a0, b0, acc00, 0, 0, 0);
        acc01 = __builtin_amdgcn_mfma_f32_16x16x32_bf16(a0, b1, acc01, 0, 0, 0);
    }

    #pragma unroll
    for (int i = 0; i < 4; ++i) {
        const int r0 = blk * BM + khalf * 4 + i;
        const int c0 = colbase + l15;
        const int c1 = c0 + 16;
        out[(size_t)r0 * UNITS + c0] = fmaxf(acc00[i], 0.f);
        out[(size_t)r0 * UNITS + c1] = fmaxf(acc01[i], 0.f);
    }
}

// ======================= f32 direct fallback (tiny ws) =======================
__global__ __launch_bounds__(256) void fused_kernel(
    const float* __restrict__ features,
    const int*   __restrict__ node,
    const int*   __restrict__ neigh,
    const unsigned short* __restrict__ Wt,
    float* __restrict__ out)
{
    __shared__ unsigned short lds[BM * KDIM];

    const int tid = threadIdx.x;
    const int blk = blockIdx.x;

    const int lane4 = tid & 31;
    const int rgrp  = tid >> 5;
    const float4* feat4 = (const float4*)features;

    #pragma unroll
    for (int rr = 0; rr < 2; ++rr) {
        const int row = rr * 8 + rgrp;
        const int g   = blk * BM + row;

        const int nidx = node[g];
        float4 nf = feat4[(size_t)nidx * 32 + lane4];

        float4 acc; acc.x = 0.f; acc.y = 0.f; acc.z = 0.f; acc.w = 0.f;
        const int* nb = neigh + (size_t)g * KNEI;
        #pragma unroll
        for (int k = 0; k < KNEI; ++k) {
            const int idx = nb[k];
            float4 v = feat4[(size_t)idx * 32 + lane4];
            acc.x += v.x; acc.y += v.y; acc.z += v.z; acc.w += v.w;
        }
        const float s = 1.0f / 25.0f;
        acc.x *= s; acc.y *= s; acc.z *= s; acc.w *= s;

        ushort4 pn; pn.x = bf16u(nf.x); pn.y = bf16u(nf.y); pn.z = bf16u(nf.z); pn.w = bf16u(nf.w);
        int off0 = (row * 512 + lane4 * 8) ^ ((row & 7) << 4);
        *(ushort4*)((char*)lds + off0) = pn;

        ushort4 pm; pm.x = bf16u(acc.x); pm.y = bf16u(acc.y); pm.z = bf16u(acc.z); pm.w = bf16u(acc.w);
        int off1 = (row * 512 + 256 + lane4 * 8) ^ ((row & 7) << 4);
        *(ushort4*)((char*)lds + off1) = pm;
    }

    __syncthreads();

    const int wv      = tid >> 6;
    const int lane    = tid & 63;
    const int l15     = lane & 15;
    const int khalf   = lane >> 4;
    const int colbase = wv * 32;

    f32x4 acc00 = {0.f,0.f,0.f,0.f};
    f32x4 acc01 = {0.f,0.f,0.f,0.f};

    #pragma unroll
    for (int ks = 0; ks < 8; ++ks) {
        const int ke = ks * 32 + khalf * 8;

        const int row0  = l15;
        const int byte0 = (row0 * 512 + ke * 2) ^ ((row0 & 7) << 4);
        bf16x8 a0 = *(const bf16x8*)((const char*)lds + byte0);

        bf16x8 b0 = *(const bf16x8*)(Wt + (size_t)(colbase + l15)      * KDIM + ke);
        bf16x8 b1 = *(const bf16x8*)(Wt + (size_t)(colbase + 16 + l15) * KDIM + ke);

        acc00 = __builtin_amdgcn_mfma_f32_16x16x32_bf16(a0, b0, acc00, 0, 0, 0);
        acc01 = __builtin_amdgcn_mfma_f32_16x16x32_bf16(a0, b1, acc01, 0, 0, 0);
    }

    #pragma unroll
    for (int i = 0; i < 4; ++i) {
        const int r0 = blk * BM + khalf * 4 + i;
        const int c0 = colbase + l15;
        const int c1 = c0 + 16;
        out[(size_t)r0 * UNITS + c0] = fmaxf(acc00[i], 0.f);
        out[(size_t)r0 * UNITS + c1] = fmaxf(acc01[i], 0.f);
    }
}

extern "C" void kernel_launch(void* const* d_in, const int* in_sizes, int n_in,
                              void* d_out, int out_size, void* d_ws, size_t ws_size,
                              hipStream_t stream) {
    const float* features = (const float*)d_in[0];
    const int*   node     = (const int*)d_in[1];
    const int*   neigh    = (const int*)d_in[2];
    const float* W        = (const float*)d_in[3];
    float* out            = (float*)d_out;

    unsigned short* Wt = (unsigned short*)d_ws;                    // 64 KB
    const size_t tab_off   = 65536;
    const size_t fp8_bytes = (size_t)NNODES * DIMF;                // 12.8 MB

    wconv_kernel<<<128, 256, 0, stream>>>(W, Wt);

    if (ws_size >= tab_off + fp8_bytes) {
        unsigned char* ftab8 = (unsigned char*)d_ws + tab_off;
        fconv_fp8_kernel<<<6250, 256, 0, stream>>>(features, (unsigned int*)ftab8);
        fused_fp8_kernel<<<NB / BM, 256, 0, stream>>>(features, ftab8, node, neigh, Wt, out);
    } else {
        fused_kernel<<<NB / BM, 256, 0, stream>>>(features, node, neigh, Wt, out);
    }
}

// Round 6
// 42.742 us; speedup vs baseline: 1.3182x; 1.1010x over previous
//
#include <hip/hip_runtime.h>
#include <hip/hip_bf16.h>

#define NNODES 100000
#define DIMF   128
#define NB     32768
#define KNEI   25
#define UNITS  128
#define KDIM   256   // 2*DIMF
#define BM     16    // rows per block

typedef __bf16 bf16x8 __attribute__((ext_vector_type(8)));
typedef float  f32x4  __attribute__((ext_vector_type(4)));
typedef float  f32x2  __attribute__((ext_vector_type(2)));
typedef unsigned short u16x8 __attribute__((ext_vector_type(8)));

__device__ __forceinline__ unsigned short bf16u(float x) {
    __hip_bfloat16 h = __float2bfloat16(x);
    return __builtin_bit_cast(unsigned short, h);
}

// features f32 -> fp8 e4m3 table (100000x128 = 12.8 MB), 8 elems/thread.
// First 128 blocks additionally convert W (256x128 f32) -> Wt (128x256 bf16 = W^T).
__global__ __launch_bounds__(256) void fconv_fp8_kernel(const float* __restrict__ F,
                                                        unsigned int* __restrict__ T,
                                                        const float* __restrict__ W,
                                                        unsigned short* __restrict__ Wt) {
    int i = blockIdx.x * 256 + threadIdx.x;   // 0..1,599,999
    const float4* f4 = (const float4*)F;
    float4 a = f4[(size_t)i * 2];
    float4 b = f4[(size_t)i * 2 + 1];
    int w0 = __builtin_amdgcn_cvt_pk_fp8_f32(a.x, a.y, 0, false);
    w0     = __builtin_amdgcn_cvt_pk_fp8_f32(a.z, a.w, w0, true);
    int w1 = __builtin_amdgcn_cvt_pk_fp8_f32(b.x, b.y, 0, false);
    w1     = __builtin_amdgcn_cvt_pk_fp8_f32(b.z, b.w, w1, true);
    uint2 o; o.x = (unsigned int)w0; o.y = (unsigned int)w1;
    *(uint2*)(T + (size_t)i * 2) = o;

    if (blockIdx.x < 128) {
        int j = blockIdx.x * 256 + threadIdx.x;   // 0..32767
        int n = j >> 8;                           // output unit
        int k = j & 255;                          // concat dim
        Wt[n * KDIM + k] = bf16u(W[k * UNITS + n]);
    }
}

// Fused: node gather from f32 features, neighbor-mean gather from fp8 table.
// MLP-maximized: all 25 indices preloaded, all 25 row-gathers in flight.
__global__ __launch_bounds__(256, 4) void fused_fp8_kernel(
    const float* __restrict__ features,
    const unsigned char* __restrict__ ftab8,   // fp8 e4m3 [NNODES][DIMF]
    const int*   __restrict__ node,
    const int*   __restrict__ neigh,
    const unsigned short* __restrict__ Wt,
    float* __restrict__ out)
{
    __shared__ unsigned short lds[BM * KDIM];   // 8 KB, XOR-swizzled concat tile

    const int tid = threadIdx.x;
    const int blk = blockIdx.x;

    // ---------------- Phase 1: gather + mean -> LDS ----------------
    const int lane8 = tid & 15;                 // dims [lane8*8, lane8*8+8)
    const int row   = tid >> 4;                 // 0..15
    const int g     = blk * BM + row;

    // node half: f32 features (issued first, independent)
    const int nidx = node[g];
    const float4* nf4 = (const float4*)(features + (size_t)nidx * DIMF + lane8 * 8);
    float4 na  = nf4[0];
    float4 nb4 = nf4[1];

    // preload all 25 neighbor indices (independent broadcast loads)
    const int* nb = neigh + (size_t)g * KNEI;
    int idx[KNEI];
    #pragma unroll
    for (int k = 0; k < KNEI; ++k) idx[k] = nb[k];

    // issue all 25 fp8-row gathers (8 B/lane each)
    const unsigned char* base8 = ftab8 + lane8 * 8;
    uint2 v[KNEI];
    #pragma unroll
    for (int k = 0; k < KNEI; ++k)
        v[k] = *(const uint2*)(base8 + (size_t)idx[k] * DIMF);

    // stash node half to LDS while gathers are in flight
    u16x8 pn;
    pn[0] = bf16u(na.x);  pn[1] = bf16u(na.y);  pn[2] = bf16u(na.z);  pn[3] = bf16u(na.w);
    pn[4] = bf16u(nb4.x); pn[5] = bf16u(nb4.y); pn[6] = bf16u(nb4.z); pn[7] = bf16u(nb4.w);
    const int off0 = (row * 512 + lane8 * 16) ^ ((row & 7) << 4);
    *(u16x8*)((char*)lds + off0) = pn;

    // decode + accumulate (HW v_cvt_pk_f32_fp8)
    float acc[8];
    #pragma unroll
    for (int j = 0; j < 8; ++j) acc[j] = 0.f;
    #pragma unroll
    for (int k = 0; k < KNEI; ++k) {
        f32x2 p0 = __builtin_amdgcn_cvt_pk_f32_fp8((int)v[k].x, false);
        f32x2 p1 = __builtin_amdgcn_cvt_pk_f32_fp8((int)v[k].x, true);
        f32x2 p2 = __builtin_amdgcn_cvt_pk_f32_fp8((int)v[k].y, false);
        f32x2 p3 = __builtin_amdgcn_cvt_pk_f32_fp8((int)v[k].y, true);
        acc[0] += p0[0]; acc[1] += p0[1]; acc[2] += p1[0]; acc[3] += p1[1];
        acc[4] += p2[0]; acc[5] += p2[1]; acc[6] += p3[0]; acc[7] += p3[1];
    }
    u16x8 pm;
    const float s = 1.0f / 25.0f;
    #pragma unroll
    for (int j = 0; j < 8; ++j) pm[j] = bf16u(acc[j] * s);
    const int off1 = (row * 512 + 256 + lane8 * 16) ^ ((row & 7) << 4);
    *(u16x8*)((char*)lds + off1) = pm;

    __syncthreads();

    // ---------------- Phase 2: MFMA GEMM (16x256) x (256x128) ----------------
    const int wv      = tid >> 6;               // 0..3 -> 32-col slice
    const int lane    = tid & 63;
    const int l15     = lane & 15;
    const int khalf   = lane >> 4;              // 0..3
    const int colbase = wv * 32;

    f32x4 acc00 = {0.f,0.f,0.f,0.f};
    f32x4 acc01 = {0.f,0.f,0.f,0.f};

    #pragma unroll
    for (int ks = 0; ks < 8; ++ks) {
        const int ke = ks * 32 + khalf * 8;

        const int row0  = l15;
        const int byte0 = (row0 * 512 + ke * 2) ^ ((row0 & 7) << 4);
        bf16x8 a0 = *(const bf16x8*)((const char*)lds + byte0);

        bf16x8 b0 = *(const bf16x8*)(Wt + (size_t)(colbase + l15)      * KDIM + ke);
        bf16x8 b1 = *(const bf16x8*)(Wt + (size_t)(colbase + 16 + l15) * KDIM + ke);

        acc00 = __builtin_amdgcn_mfma_f32_16x16x32_bf16(a0, b0, acc00, 0, 0, 0);
        acc01 = __builtin_amdgcn_mfma_f32_16x16x32_bf16(a0, b1, acc01, 0, 0, 0);
    }

    #pragma unroll
    for (int i = 0; i < 4; ++i) {
        const int r0 = blk * BM + khalf * 4 + i;
        const int c0 = colbase + l15;
        const int c1 = c0 + 16;
        out[(size_t)r0 * UNITS + c0] = fmaxf(acc00[i], 0.f);
        out[(size_t)r0 * UNITS + c1] = fmaxf(acc01[i], 0.f);
    }
}

// ======================= f32 direct fallback (tiny ws) =======================
__global__ void wconv_kernel(const float* __restrict__ W,
                             unsigned short* __restrict__ Wt) {
    int i = blockIdx.x * 256 + threadIdx.x;
    int n = i >> 8;
    int k = i & 255;
    Wt[n * KDIM + k] = bf16u(W[k * UNITS + n]);
}

__global__ __launch_bounds__(256) void fused_kernel(
    const float* __restrict__ features,
    const int*   __restrict__ node,
    const int*   __restrict__ neigh,
    const unsigned short* __restrict__ Wt,
    float* __restrict__ out)
{
    __shared__ unsigned short lds[BM * KDIM];

    const int tid = threadIdx.x;
    const int blk = blockIdx.x;

    const int lane4 = tid & 31;
    const int rgrp  = tid >> 5;
    const float4* feat4 = (const float4*)features;

    #pragma unroll
    for (int rr = 0; rr < 2; ++rr) {
        const int row = rr * 8 + rgrp;
        const int g   = blk * BM + row;

        const int nidx = node[g];
        float4 nf = feat4[(size_t)nidx * 32 + lane4];

        float4 acc; acc.x = 0.f; acc.y = 0.f; acc.z = 0.f; acc.w = 0.f;
        const int* nb = neigh + (size_t)g * KNEI;
        #pragma unroll
        for (int k = 0; k < KNEI; ++k) {
            const int idx = nb[k];
            float4 vv = feat4[(size_t)idx * 32 + lane4];
            acc.x += vv.x; acc.y += vv.y; acc.z += vv.z; acc.w += vv.w;
        }
        const float s = 1.0f / 25.0f;
        acc.x *= s; acc.y *= s; acc.z *= s; acc.w *= s;

        ushort4 pn; pn.x = bf16u(nf.x); pn.y = bf16u(nf.y); pn.z = bf16u(nf.z); pn.w = bf16u(nf.w);
        int off0 = (row * 512 + lane4 * 8) ^ ((row & 7) << 4);
        *(ushort4*)((char*)lds + off0) = pn;

        ushort4 pm; pm.x = bf16u(acc.x); pm.y = bf16u(acc.y); pm.z = bf16u(acc.z); pm.w = bf16u(acc.w);
        int off1 = (row * 512 + 256 + lane4 * 8) ^ ((row & 7) << 4);
        *(ushort4*)((char*)lds + off1) = pm;
    }

    __syncthreads();

    const int wv      = tid >> 6;
    const int lane    = tid & 63;
    const int l15     = lane & 15;
    const int khalf   = lane >> 4;
    const int colbase = wv * 32;

    f32x4 acc00 = {0.f,0.f,0.f,0.f};
    f32x4 acc01 = {0.f,0.f,0.f,0.f};

    #pragma unroll
    for (int ks = 0; ks < 8; ++ks) {
        const int ke = ks * 32 + khalf * 8;

        const int row0  = l15;
        const int byte0 = (row0 * 512 + ke * 2) ^ ((row0 & 7) << 4);
        bf16x8 a0 = *(const bf16x8*)((const char*)lds + byte0);

        bf16x8 b0 = *(const bf16x8*)(Wt + (size_t)(colbase + l15)      * KDIM + ke);
        bf16x8 b1 = *(const bf16x8*)(Wt + (size_t)(colbase + 16 + l15) * KDIM + ke);

        acc00 = __builtin_amdgcn_mfma_f32_16x16x32_bf16(a0, b0, acc00, 0, 0, 0);
        acc01 = __builtin_amdgcn_mfma_f32_16x16x32_bf16(a0, b1, acc01, 0, 0, 0);
    }

    #pragma unroll
    for (int i = 0; i < 4; ++i) {
        const int r0 = blk * BM + khalf * 4 + i;
        const int c0 = colbase + l15;
        const int c1 = c0 + 16;
        out[(size_t)r0 * UNITS + c0] = fmaxf(acc00[i], 0.f);
        out[(size_t)r0 * UNITS + c1] = fmaxf(acc01[i], 0.f);
    }
}

extern "C" void kernel_launch(void* const* d_in, const int* in_sizes, int n_in,
                              void* d_out, int out_size, void* d_ws, size_t ws_size,
                              hipStream_t stream) {
    const float* features = (const float*)d_in[0];
    const int*   node     = (const int*)d_in[1];
    const int*   neigh    = (const int*)d_in[2];
    const float* W        = (const float*)d_in[3];
    float* out            = (float*)d_out;

    unsigned short* Wt = (unsigned short*)d_ws;                    // 64 KB
    const size_t tab_off   = 65536;
    const size_t fp8_bytes = (size_t)NNODES * DIMF;                // 12.8 MB

    if (ws_size >= tab_off + fp8_bytes) {
        unsigned char* ftab8 = (unsigned char*)d_ws + tab_off;
        fconv_fp8_kernel<<<6250, 256, 0, stream>>>(features, (unsigned int*)ftab8, W, Wt);
        fused_fp8_kernel<<<NB / BM, 256, 0, stream>>>(features, ftab8, node, neigh, Wt, out);
    } else {
        wconv_kernel<<<128, 256, 0, stream>>>(W, Wt);
        fused_kernel<<<NB / BM, 256, 0, stream>>>(features, node, neigh, Wt, out);
    }
}